// Round 7
// baseline (633.680 us; speedup 1.0000x reference)
//
#include <hip/hip_runtime.h>

typedef __attribute__((ext_vector_type(8))) short short8;
typedef __attribute__((ext_vector_type(4))) float f32x4;
typedef unsigned short u16;
typedef unsigned int u32;
typedef unsigned long long u64;

#define MFMA16(a, b, c) __builtin_amdgcn_mfma_f32_16x16x32_bf16((a), (b), (c), 0, 0, 0)
#define SCALE 0.044194173824159216f /* 1/sqrt(512) */

__device__ __forceinline__ u16 f2bf(float f) {
    u32 u = __float_as_uint(f);
    u = (u + 0x7fffu + ((u >> 16) & 1u)) >> 16; // RNE
    return (u16)u;
}

// pack 8 f32 -> 8 bf16 (RNE) via v_cvt_pk_bf16_f32 (no builtin on gfx950)
__device__ __forceinline__ short8 pack8(f32x4 x, f32x4 y) {
    union { u32 w[4]; short8 s; } u;
    asm("v_cvt_pk_bf16_f32 %0, %1, %2" : "=v"(u.w[0]) : "v"(x[0]), "v"(x[1]));
    asm("v_cvt_pk_bf16_f32 %0, %1, %2" : "=v"(u.w[1]) : "v"(x[2]), "v"(x[3]));
    asm("v_cvt_pk_bf16_f32 %0, %1, %2" : "=v"(u.w[2]) : "v"(y[0]), "v"(y[1]));
    asm("v_cvt_pk_bf16_f32 %0, %1, %2" : "=v"(u.w[3]) : "v"(y[2]), "v"(y[3]));
    return u.s;
}

// LDS-only barrier (no vmcnt drain; NT stores never re-read in-kernel)
__device__ __forceinline__ void ldsbar() {
    asm volatile("s_waitcnt lgkmcnt(0)" ::: "memory");
    __builtin_amdgcn_s_barrier();
}

// XOR-swizzled LDS index for an [8][1024] f32 tile
__device__ __forceinline__ int swz(int r, int c) {
    return (r << 10) + (c ^ ((r & 7) << 2));
}

struct CvtArgs {
    const float* s[7];
    u16* d[7];
};

// One launch converts q,k,v (y=0..2, 524288 float4) + Wq,Wk,Wv,Wo (y=3..6, 65536)
__global__ __launch_bounds__(256) void cvt_all(CvtArgs a) {
    int which = blockIdx.y;
    int n4 = (which < 3) ? 524288 : 65536;
    int i = blockIdx.x * 256 + threadIdx.x;
    if (i >= n4) return;
    f32x4 v = __builtin_nontemporal_load((const f32x4*)a.s[which] + i);
    u64 p = (u64)f2bf(v[0])
          | ((u64)f2bf(v[1]) << 16)
          | ((u64)f2bf(v[2]) << 32)
          | ((u64)f2bf(v[3]) << 48);
    ((u64*)a.d[which])[i] = p;
}

// rel[r,c] = sum_k pos_emb[r,k] * Wp[c,k] + bp[c], r<2047, c<64 -> bf16
__global__ __launch_bounds__(256) void rel_kernel(const float* __restrict__ pos_emb,
                                                  const float* __restrict__ Wp,
                                                  const float* __restrict__ bp,
                                                  u16* __restrict__ rel) {
    int idx = blockIdx.x * 256 + threadIdx.x;
    if (idx >= 2047 * 64) return;
    int r = idx >> 6, c = idx & 63;
    const float* pe = pos_emb + r * 64;
    const float* w  = Wp + c * 64;
    float acc = bp[c];
#pragma unroll
    for (int k = 0; k < 64; k++) acc += pe[k] * w[k];
    rel[r * 64 + c] = f2bf(acc);
}

// Fused q/k/v projections: grid (64, 8, 3) = 1536 blocks -> 6 blocks/CU
// (3x the latency hiding of three separate 512-block launches).
// z=0: q = query@Wq^T (M=4096,N=512) -> [B,H,S,dh]
// z=1: k = key@Wk^T                  -> [B,H,S,dh]
// z=2: vT = Wv@value^T (M=512,N=4096)-> [B,H,dh,S]
struct ProjArgs {
    const u16* A[3];
    const u16* B[3];
    const float* bias[3];
    u16* out[3];
};
__global__ __launch_bounds__(256) void proj_all(ProjArgs pa) {
    int z = blockIdx.z;
    int tid = threadIdx.x;
    int w = tid >> 6, lane = tid & 63;
    int wi = w >> 1, wj = w & 1;
    int qd = lane >> 4, ln = lane & 15;
    int mt = (z == 2) ? blockIdx.y : blockIdx.x;
    int nt = (z == 2) ? blockIdx.x : blockIdx.y;
    int m_base = mt * 64 + wi * 32;
    int n_base = nt * 64 + wj * 32;
    const u16* A = pa.A[z];
    const u16* B = pa.B[z];
    const float* bias = pa.bias[z];
    u16* out = pa.out[z];
    const int K = 512;
    f32x4 acc[2][2] = {};
    const u16* a0p = A + (long)(m_base + ln) * K + qd * 8;
    const u16* a1p = a0p + 16 * K;
    const u16* b0p = B + (long)(n_base + ln) * K + qd * 8;
    const u16* b1p = b0p + 16 * K;
    for (int kc = 0; kc < K; kc += 32) {
        short8 a0 = *(const short8*)(a0p + kc);
        short8 a1 = *(const short8*)(a1p + kc);
        short8 b0 = *(const short8*)(b0p + kc);
        short8 b1 = *(const short8*)(b1p + kc);
        acc[0][0] = MFMA16(a0, b0, acc[0][0]);
        acc[0][1] = MFMA16(a0, b1, acc[0][1]);
        acc[1][0] = MFMA16(a1, b0, acc[1][0]);
        acc[1][1] = MFMA16(a1, b1, acc[1][1]);
    }
#pragma unroll
    for (int i = 0; i < 2; i++)
#pragma unroll
        for (int j = 0; j < 2; j++)
#pragma unroll
            for (int r = 0; r < 4; r++) {
                int m = m_base + i * 16 + qd * 4 + r;
                int n = n_base + j * 16 + ln;
                float v = acc[i][j][r];
                if (z < 2) {
                    v += bias[n];
                    int b = m >> 10, s = m & 1023, h = n >> 6, d = n & 63;
                    out[(((long)(b * 8 + h) << 10) + s) * 64 + d] = f2bf(v);
                } else {
                    v += bias[m];
                    int b = n >> 10, t = n & 1023, h = m >> 6, d = m & 63;
                    out[(((long)(b * 8 + h) * 64 + d) << 10) + t] = f2bf(v);
                }
            }
}

// Final projection: C = ctx@Wo^T + bo, fp32 out (NT).
__global__ __launch_bounds__(256) void gemm_final(const u16* __restrict__ A,
                                                  const u16* __restrict__ B,
                                                  const float* __restrict__ bias,
                                                  float* __restrict__ Cout) {
    int tid = threadIdx.x;
    int w = tid >> 6, lane = tid & 63;
    int wi = w >> 1, wj = w & 1;
    int qd = lane >> 4, ln = lane & 15;
    int m_base = blockIdx.x * 64 + wi * 32;
    int n_base = blockIdx.y * 64 + wj * 32;
    const int K = 512, N = 512;
    f32x4 acc[2][2] = {};
    const u16* a0p = A + (long)(m_base + ln) * K + qd * 8;
    const u16* a1p = a0p + 16 * K;
    const u16* b0p = B + (long)(n_base + ln) * K + qd * 8;
    const u16* b1p = b0p + 16 * K;
    for (int kc = 0; kc < K; kc += 32) {
        short8 a0 = *(const short8*)(a0p + kc);
        short8 a1 = *(const short8*)(a1p + kc);
        short8 b0 = *(const short8*)(b0p + kc);
        short8 b1 = *(const short8*)(b1p + kc);
        acc[0][0] = MFMA16(a0, b0, acc[0][0]);
        acc[0][1] = MFMA16(a0, b1, acc[0][1]);
        acc[1][0] = MFMA16(a1, b0, acc[1][0]);
        acc[1][1] = MFMA16(a1, b1, acc[1][1]);
    }
#pragma unroll
    for (int i = 0; i < 2; i++)
#pragma unroll
        for (int j = 0; j < 2; j++)
#pragma unroll
            for (int r = 0; r < 4; r++) {
                int m = m_base + i * 16 + qd * 4 + r;
                int n = n_base + j * 16 + ln;
                __builtin_nontemporal_store(acc[i][j][r] + bias[n],
                                            Cout + (long)m * N + n);
            }
}

// One block per (b, h, 8-row s-tile): 4096 blocks, 32 KB LDS -> 5 blocks/CU
// (vs 2 at 16-row/64KB). MFMA fragments are half-empty (rows 8-15 discarded);
// MFMA is ~3% of budget, occupancy is the binding constraint. R6 choreography
// retained: LDS-only barriers, NT stores deferred past subsequent loads.
__global__ __launch_bounds__(256) void score_kernel(const u16* __restrict__ qws,
                                                    const u16* __restrict__ kws,
                                                    const u16* __restrict__ vtws,
                                                    const u16* __restrict__ relws,
                                                    float* __restrict__ out_attn,
                                                    float* __restrict__ out_cont,
                                                    float* __restrict__ out_pos,
                                                    u16* __restrict__ ctx) {
    __shared__ float sc[8 * 1024]; // 32 KB, XOR-swizzled via swz()
    // XCD remap: l%8 = xcd, 4 bh per xcd, 128 s-tiles per bh
    int l = blockIdx.x;
    int xcd = l & 7, i0 = l >> 3;
    int bh = (xcd << 2) + (i0 >> 7);
    int st = i0 & 127;
    int b = bh >> 3, h = bh & 7;
    int s0 = st * 8;
    int tid = threadIdx.x;
    int w = tid >> 6, lane = tid & 63, qd = lane >> 4, ln = lane & 15;
    int row = tid >> 5, g = tid & 31; // softmax: 32 lanes per row, 8 rows

    const u16* qbase  = qws + ((long)bh << 10) * 64;   // [1024][64]
    const u16* kbase  = kws + ((long)bh << 10) * 64;   // [1024][64]
    const u16* vtbase = vtws + ((long)bh << 6) * 1024; // [64][1024]
    float* attn_base = out_attn + ((long)bh << 20) + (long)s0 * 1024;
    float* cont_base = out_cont + ((long)bh << 20) + (long)s0 * 1024;
    float* pos_base  = out_pos  + ((long)bh << 20) + (long)s0 * 1024;

    // q fragment rows s0+ln; ln>=8 rows belong to the next tile (results
    // discarded; reads stay inside d_ws)
    short8 qa0 = *(const short8*)(qbase + (s0 + ln) * 64 + qd * 8);
    short8 qa1 = *(const short8*)(qbase + (s0 + ln) * 64 + 32 + qd * 8);

    // ---- Phase 1: content -> sc rows 0..7. Wave w: t in [w*256, w*256+256) ----
    for (int tt = 0; tt < 16; tt++) {
        int t0 = w * 256 + tt * 16;
        short8 kb0 = *(const short8*)(kbase + (t0 + ln) * 64 + qd * 8);
        short8 kb1 = *(const short8*)(kbase + (t0 + ln) * 64 + 32 + qd * 8);
        f32x4 acc = {};
        acc = MFMA16(qa0, kb0, acc);
        acc = MFMA16(qa1, kb1, acc);
        if (qd < 2) {
#pragma unroll
            for (int r = 0; r < 4; r++) sc[swz(qd * 4 + r, t0 + ln)] = acc[r];
        }
    }
    ldsbar();

    // ---- Cache cont in regs (stores deferred past phase-2 loads) ----
    f32x4 csave[8];
#pragma unroll
    for (int i = 0; i < 8; i++) csave[i] = *(const f32x4*)&sc[swz(i, tid * 4)];
    ldsbar();

    // ---- Phase 2: pos accumulate. t = rt*16 + ln + sl - 7 ----
    int rbase = 1016 - s0;
    for (int rt = w; rt < 65; rt += 4) {
        int r0 = rbase + rt * 16;
        short8 rb0 = *(const short8*)(relws + (r0 + ln) * 64 + qd * 8);
        short8 rb1 = *(const short8*)(relws + (r0 + ln) * 64 + 32 + qd * 8);
        f32x4 acc = {};
        acc = MFMA16(qa0, rb0, acc);
        acc = MFMA16(qa1, rb1, acc);
#pragma unroll
        for (int r = 0; r < 4; r++) {
            int sl = qd * 4 + r;
            int t = rt * 16 + ln + sl - 7;
            if (sl < 8 && t >= 0 && t < 1024) sc[swz(sl, t)] += acc[r];
        }
    }
    // cont NT stores issued after ALL rel loads (in-order vmcnt)
#pragma unroll
    for (int i = 0; i < 8; i++)
        __builtin_nontemporal_store(csave[i], (f32x4*)&cont_base[i * 1024 + tid * 4]);
    ldsbar();

    // ---- Phase 3a: pos dump (= sc - cont) + softmax reads ----
#pragma unroll
    for (int i = 0; i < 8; i++) {
        f32x4 v = *(const f32x4*)&sc[swz(i, tid * 4)];
        __builtin_nontemporal_store(v - csave[i], (f32x4*)&pos_base[i * 1024 + tid * 4]);
    }
    float ev[32];
    float inv;
    {
        float mx = -1e30f;
#pragma unroll
        for (int i = 0; i < 32; i++) {
            float v = sc[swz(row, g + 32 * i)] * SCALE;
            ev[i] = v;
            mx = fmaxf(mx, v);
        }
        for (int off = 1; off < 32; off <<= 1) mx = fmaxf(mx, __shfl_xor(mx, off, 64));
        float sum = 0.f;
#pragma unroll
        for (int i = 0; i < 32; i++) {
            float e = __expf(ev[i] - mx);
            ev[i] = e;
            sum += e;
        }
        for (int off = 1; off < 32; off <<= 1) sum += __shfl_xor(sum, off, 64);
        inv = 1.0f / sum;
    }
    ldsbar(); // pre-softmax sc reads complete before writeback

    // ---- Phase 3b: writeback attn values ----
#pragma unroll
    for (int i = 0; i < 32; i++) sc[swz(row, g + 32 * i)] = ev[i] * inv;
    ldsbar();

    // ---- Phase 4: o = attn @ v. Wave w -> d-subtile [w*16, w*16+16) ----
    {
        const u16* vrow = vtbase + (w * 16 + ln) * 1024 + qd * 8;
        f32x4 oacc = {};
        for (int kt = 0; kt < 32; kt++) {
            f32x4 x = *(const f32x4*)&sc[swz(ln & 7, kt * 32 + qd * 8)];
            f32x4 y = *(const f32x4*)&sc[swz(ln & 7, kt * 32 + qd * 8 + 4)];
            short8 a = pack8(x, y);
            short8 bf = *(const short8*)(vrow + kt * 32);
            oacc = MFMA16(a, bf, oacc);
        }
#pragma unroll
        for (int r = 0; r < 4; r++) {
            int sl = qd * 4 + r;
            if (sl < 8) {
                int d = w * 16 + ln;
                ctx[((long)(b * 1024 + s0 + sl)) * 512 + h * 64 + d] = f2bf(oacc[r]);
            }
        }
    }

    // ---- attn dump last: drains at kernel end, overlapping next block ----
#pragma unroll
    for (int i = 0; i < 8; i++) {
        f32x4 v = *(const f32x4*)&sc[swz(i, tid * 4)];
        __builtin_nontemporal_store(v, (f32x4*)&attn_base[i * 1024 + tid * 4]);
    }
}

extern "C" void kernel_launch(void* const* d_in, const int* in_sizes, int n_in,
                              void* d_out, int out_size, void* d_ws, size_t ws_size,
                              hipStream_t stream) {
    (void)in_sizes; (void)n_in; (void)out_size; (void)ws_size;
    const float* query   = (const float*)d_in[0];
    const float* key     = (const float*)d_in[1];
    const float* value   = (const float*)d_in[2];
    const float* pos_emb = (const float*)d_in[3];
    const float* Wq = (const float*)d_in[4];
    const float* bq = (const float*)d_in[5];
    const float* Wk = (const float*)d_in[6];
    const float* bk = (const float*)d_in[7];
    const float* Wv = (const float*)d_in[8];
    const float* bv = (const float*)d_in[9];
    const float* Wo = (const float*)d_in[10];
    const float* bo = (const float*)d_in[11];
    const float* Wp = (const float*)d_in[12];
    const float* bp = (const float*)d_in[13];

    // workspace layout (bf16 u16 elements)
    u16* qin  = (u16*)d_ws;            // 4096*512
    u16* kin  = qin + 4096 * 512;
    u16* vin  = kin + 4096 * 512;
    u16* wqb  = vin + 4096 * 512;      // 512*512 each
    u16* wkb  = wqb + 512 * 512;
    u16* wvb  = wkb + 512 * 512;
    u16* wob  = wvb + 512 * 512;
    u16* relb = wob + 512 * 512;       // 2048*64 (row 2047 read-garbage, discarded)
    u16* qws  = relb + 2048 * 64;      // [B,H,S,64]
    u16* kws  = qws + 4 * 8 * 1024 * 64;
    u16* vtws = kws + 4 * 8 * 1024 * 64; // [B,H,64,S]
    u16* ctx  = qin; // alias: qin dead after q-projection

    float* out  = (float*)d_out;
    float* attn = out + 2097152;
    float* cont = attn + 33554432;
    float* pos  = cont + 33554432;

    CvtArgs ca;
    ca.s[0] = query; ca.d[0] = qin;
    ca.s[1] = key;   ca.d[1] = kin;
    ca.s[2] = value; ca.d[2] = vin;
    ca.s[3] = Wq;    ca.d[3] = wqb;
    ca.s[4] = Wk;    ca.d[4] = wkb;
    ca.s[5] = Wv;    ca.d[5] = wvb;
    ca.s[6] = Wo;    ca.d[6] = wob;
    cvt_all<<<dim3(2048, 7), 256, 0, stream>>>(ca);
    rel_kernel<<<512, 256, 0, stream>>>(pos_emb, Wp, bp, relb);

    ProjArgs pa;
    pa.A[0] = qin;  pa.B[0] = wqb; pa.bias[0] = bq; pa.out[0] = qws;
    pa.A[1] = kin;  pa.B[1] = wkb; pa.bias[1] = bk; pa.out[1] = kws;
    pa.A[2] = wvb;  pa.B[2] = vin; pa.bias[2] = bv; pa.out[2] = vtws;
    proj_all<<<dim3(64, 8, 3), 256, 0, stream>>>(pa);

    score_kernel<<<4096, 256, 0, stream>>>(qws, kws, vtws, relb, attn, cont, pos, ctx);

    gemm_final<<<dim3(64, 8), 256, 0, stream>>>(ctx, wob, bo, out);
}

// Round 8
// 559.168 us; speedup vs baseline: 1.1333x; 1.1333x over previous
//
#include <hip/hip_runtime.h>

typedef __attribute__((ext_vector_type(8))) short short8;
typedef __attribute__((ext_vector_type(4))) float f32x4;
typedef unsigned short u16;
typedef unsigned int u32;
typedef unsigned long long u64;

#define MFMA16(a, b, c) __builtin_amdgcn_mfma_f32_16x16x32_bf16((a), (b), (c), 0, 0, 0)
#define SCALE 0.044194173824159216f /* 1/sqrt(512) */

__device__ __forceinline__ u16 f2bf(float f) {
    u32 u = __float_as_uint(f);
    u = (u + 0x7fffu + ((u >> 16) & 1u)) >> 16; // RNE
    return (u16)u;
}

// pack 8 f32 -> 8 bf16 (RNE) via v_cvt_pk_bf16_f32 (no builtin on gfx950)
__device__ __forceinline__ short8 pack8(f32x4 x, f32x4 y) {
    union { u32 w[4]; short8 s; } u;
    asm("v_cvt_pk_bf16_f32 %0, %1, %2" : "=v"(u.w[0]) : "v"(x[0]), "v"(x[1]));
    asm("v_cvt_pk_bf16_f32 %0, %1, %2" : "=v"(u.w[1]) : "v"(x[2]), "v"(x[3]));
    asm("v_cvt_pk_bf16_f32 %0, %1, %2" : "=v"(u.w[2]) : "v"(y[0]), "v"(y[1]));
    asm("v_cvt_pk_bf16_f32 %0, %1, %2" : "=v"(u.w[3]) : "v"(y[2]), "v"(y[3]));
    return u.s;
}

// LDS-only barrier (no vmcnt drain; NT stores never re-read in-kernel)
__device__ __forceinline__ void ldsbar() {
    asm volatile("s_waitcnt lgkmcnt(0)" ::: "memory");
    __builtin_amdgcn_s_barrier();
}

// XOR-swizzled LDS index for a [16][1024] f32 tile
__device__ __forceinline__ int swz(int r, int c) {
    return (r << 10) + (c ^ ((r & 7) << 2));
}

// y=0..2: q/k/v fp32->bf16 (2048 x-blocks); y=3..6: weights (256 x-blocks);
// y=7: rel = pos_emb@Wp^T+bp (512 x-blocks). Merged to cut launch count.
struct PrepArgs {
    const float* s[7];
    u16* d[7];
    const float* pos_emb;
    const float* Wp;
    const float* bp;
    u16* rel;
};
__global__ __launch_bounds__(256) void prep_all(PrepArgs a) {
    int which = blockIdx.y;
    int tid = threadIdx.x;
    if (which == 7) {
        int idx = blockIdx.x * 256 + tid;
        if (idx >= 2047 * 64) return;
        int r = idx >> 6, c = idx & 63;
        const float* pe = a.pos_emb + r * 64;
        const float* w  = a.Wp + c * 64;
        float acc = a.bp[c];
#pragma unroll
        for (int k = 0; k < 64; k++) acc += pe[k] * w[k];
        a.rel[r * 64 + c] = f2bf(acc);
        return;
    }
    int n4 = (which < 3) ? 524288 : 65536;
    int i = blockIdx.x * 256 + tid;
    if (i >= n4) return;
    f32x4 v = __builtin_nontemporal_load((const f32x4*)a.s[which] + i);
    u64 p = (u64)f2bf(v[0])
          | ((u64)f2bf(v[1]) << 16)
          | ((u64)f2bf(v[2]) << 32)
          | ((u64)f2bf(v[3]) << 48);
    ((u64*)a.d[which])[i] = p;
}

// Fused q/k/v projections: grid (64, 8, 3) = 1536 blocks -> 6 blocks/CU.
// z=0: q = query@Wq^T -> [B,H,S,dh]; z=1: k; z=2: vT = Wv@value^T -> [B,H,dh,S]
struct ProjArgs {
    const u16* A[3];
    const u16* B[3];
    const float* bias[3];
    u16* out[3];
};
__global__ __launch_bounds__(256) void proj_all(ProjArgs pa) {
    int z = blockIdx.z;
    int tid = threadIdx.x;
    int w = tid >> 6, lane = tid & 63;
    int wi = w >> 1, wj = w & 1;
    int qd = lane >> 4, ln = lane & 15;
    int mt = (z == 2) ? blockIdx.y : blockIdx.x;
    int nt = (z == 2) ? blockIdx.x : blockIdx.y;
    int m_base = mt * 64 + wi * 32;
    int n_base = nt * 64 + wj * 32;
    const u16* A = pa.A[z];
    const u16* B = pa.B[z];
    const float* bias = pa.bias[z];
    u16* out = pa.out[z];
    const int K = 512;
    f32x4 acc[2][2] = {};
    const u16* a0p = A + (long)(m_base + ln) * K + qd * 8;
    const u16* a1p = a0p + 16 * K;
    const u16* b0p = B + (long)(n_base + ln) * K + qd * 8;
    const u16* b1p = b0p + 16 * K;
    for (int kc = 0; kc < K; kc += 32) {
        short8 a0 = *(const short8*)(a0p + kc);
        short8 a1 = *(const short8*)(a1p + kc);
        short8 b0 = *(const short8*)(b0p + kc);
        short8 b1 = *(const short8*)(b1p + kc);
        acc[0][0] = MFMA16(a0, b0, acc[0][0]);
        acc[0][1] = MFMA16(a0, b1, acc[0][1]);
        acc[1][0] = MFMA16(a1, b0, acc[1][0]);
        acc[1][1] = MFMA16(a1, b1, acc[1][1]);
    }
#pragma unroll
    for (int i = 0; i < 2; i++)
#pragma unroll
        for (int j = 0; j < 2; j++)
#pragma unroll
            for (int r = 0; r < 4; r++) {
                int m = m_base + i * 16 + qd * 4 + r;
                int n = n_base + j * 16 + ln;
                float v = acc[i][j][r];
                if (z < 2) {
                    v += bias[n];
                    int b = m >> 10, s = m & 1023, h = n >> 6, d = n & 63;
                    out[(((long)(b * 8 + h) << 10) + s) * 64 + d] = f2bf(v);
                } else {
                    v += bias[m];
                    int b = n >> 10, t = n & 1023, h = m >> 6, d = m & 63;
                    out[(((long)(b * 8 + h) * 64 + d) << 10) + t] = f2bf(v);
                }
            }
}

// Final projection: C = ctx@Wo^T + bo, fp32 out (NT).
__global__ __launch_bounds__(256) void gemm_final(const u16* __restrict__ A,
                                                  const u16* __restrict__ B,
                                                  const float* __restrict__ bias,
                                                  float* __restrict__ Cout) {
    int tid = threadIdx.x;
    int w = tid >> 6, lane = tid & 63;
    int wi = w >> 1, wj = w & 1;
    int qd = lane >> 4, ln = lane & 15;
    int m_base = blockIdx.x * 64 + wi * 32;
    int n_base = blockIdx.y * 64 + wj * 32;
    const int K = 512, N = 512;
    f32x4 acc[2][2] = {};
    const u16* a0p = A + (long)(m_base + ln) * K + qd * 8;
    const u16* a1p = a0p + 16 * K;
    const u16* b0p = B + (long)(n_base + ln) * K + qd * 8;
    const u16* b1p = b0p + 16 * K;
    for (int kc = 0; kc < K; kc += 32) {
        short8 a0 = *(const short8*)(a0p + kc);
        short8 a1 = *(const short8*)(a1p + kc);
        short8 b0 = *(const short8*)(b0p + kc);
        short8 b1 = *(const short8*)(b1p + kc);
        acc[0][0] = MFMA16(a0, b0, acc[0][0]);
        acc[0][1] = MFMA16(a0, b1, acc[0][1]);
        acc[1][0] = MFMA16(a1, b0, acc[1][0]);
        acc[1][1] = MFMA16(a1, b1, acc[1][1]);
    }
#pragma unroll
    for (int i = 0; i < 2; i++)
#pragma unroll
        for (int j = 0; j < 2; j++)
#pragma unroll
            for (int r = 0; r < 4; r++) {
                int m = m_base + i * 16 + qd * 4 + r;
                int n = n_base + j * 16 + ln;
                __builtin_nontemporal_store(acc[i][j][r] + bias[n],
                                            Cout + (long)m * N + n);
            }
}

// R6-exact score kernel (best measured): 16-row s-tiles, 64 KB LDS, LDS-only
// barriers, NT stores deferred past subsequent loads, XCD-affinity remap.
__global__ __launch_bounds__(256) void score_kernel(const u16* __restrict__ qws,
                                                    const u16* __restrict__ kws,
                                                    const u16* __restrict__ vtws,
                                                    const u16* __restrict__ relws,
                                                    float* __restrict__ out_attn,
                                                    float* __restrict__ out_cont,
                                                    float* __restrict__ out_pos,
                                                    u16* __restrict__ ctx) {
    __shared__ float sc[16 * 1024]; // 64 KB, XOR-swizzled via swz()
    int l = blockIdx.x;
    int xcd = l & 7, i0 = l >> 3;
    int bh = (xcd << 2) + (i0 >> 6);
    int st = i0 & 63;
    int b = bh >> 3, h = bh & 7;
    int s0 = st * 16;
    int tid = threadIdx.x;
    int w = tid >> 6, lane = tid & 63, qd = lane >> 4, ln = lane & 15;
    int row = tid >> 4, g = tid & 15;

    const u16* qbase  = qws + ((long)bh << 10) * 64;   // [1024][64]
    const u16* kbase  = kws + ((long)bh << 10) * 64;   // [1024][64]
    const u16* vtbase = vtws + ((long)bh << 6) * 1024; // [64][1024]
    float* attn_base = out_attn + ((long)bh << 20) + (long)s0 * 1024;
    float* cont_base = out_cont + ((long)bh << 20) + (long)s0 * 1024;
    float* pos_base  = out_pos  + ((long)bh << 20) + (long)s0 * 1024;

    short8 qa0 = *(const short8*)(qbase + (s0 + ln) * 64 + qd * 8);
    short8 qa1 = *(const short8*)(qbase + (s0 + ln) * 64 + 32 + qd * 8);

    // ---- Phase 1: content -> sc. Wave w covers t in [w*256, w*256+256) ----
    for (int tt = 0; tt < 16; tt++) {
        int t0 = w * 256 + tt * 16;
        short8 kb0 = *(const short8*)(kbase + (t0 + ln) * 64 + qd * 8);
        short8 kb1 = *(const short8*)(kbase + (t0 + ln) * 64 + 32 + qd * 8);
        f32x4 acc = {};
        acc = MFMA16(qa0, kb0, acc);
        acc = MFMA16(qa1, kb1, acc);
#pragma unroll
        for (int r = 0; r < 4; r++) sc[swz(qd * 4 + r, t0 + ln)] = acc[r];
    }
    ldsbar();

    // ---- Cache cont in regs (stores deferred past phase-2 loads) ----
    f32x4 csave[16];
#pragma unroll
    for (int i = 0; i < 16; i++) csave[i] = *(const f32x4*)&sc[swz(i, tid * 4)];
    ldsbar();

    // ---- Phase 2: pos accumulate into sc. 65 r-subtiles ----
    int rbase = 1008 - s0;
    for (int rt = w; rt < 65; rt += 4) {
        int r0 = rbase + rt * 16;
        short8 rb0 = *(const short8*)(relws + (r0 + ln) * 64 + qd * 8);
        short8 rb1 = *(const short8*)(relws + (r0 + ln) * 64 + 32 + qd * 8);
        f32x4 acc = {};
        acc = MFMA16(qa0, rb0, acc);
        acc = MFMA16(qa1, rb1, acc);
#pragma unroll
        for (int r = 0; r < 4; r++) {
            int sl = qd * 4 + r;
            int t = rt * 16 + ln + sl - 15;
            if (t >= 0 && t < 1024) sc[swz(sl, t)] += acc[r];
        }
    }
#pragma unroll
    for (int i = 0; i < 16; i++)
        __builtin_nontemporal_store(csave[i], (f32x4*)&cont_base[i * 1024 + tid * 4]);
    ldsbar();

    // ---- Phase 3a: pos dump (= sc - cont) + softmax reads ----
#pragma unroll
    for (int i = 0; i < 16; i++) {
        f32x4 v = *(const f32x4*)&sc[swz(i, tid * 4)];
        __builtin_nontemporal_store(v - csave[i], (f32x4*)&pos_base[i * 1024 + tid * 4]);
    }
    float ev[64];
    float inv;
    {
        float mx = -1e30f;
#pragma unroll
        for (int i = 0; i < 64; i++) {
            float v = sc[swz(row, g + 16 * i)] * SCALE;
            ev[i] = v;
            mx = fmaxf(mx, v);
        }
        for (int off = 1; off < 16; off <<= 1) mx = fmaxf(mx, __shfl_xor(mx, off, 64));
        float sum = 0.f;
#pragma unroll
        for (int i = 0; i < 64; i++) {
            float e = __expf(ev[i] - mx);
            ev[i] = e;
            sum += e;
        }
        for (int off = 1; off < 16; off <<= 1) sum += __shfl_xor(sum, off, 64);
        inv = 1.0f / sum;
    }
    ldsbar();

    // ---- Phase 3b: writeback attn values into sc ----
#pragma unroll
    for (int i = 0; i < 64; i++) sc[swz(row, g + 16 * i)] = ev[i] * inv;
    ldsbar();

    // ---- Phase 4: o = attn @ v. Wave w -> d-subtile [w*16, w*16+16) ----
    {
        const u16* vrow = vtbase + (w * 16 + ln) * 1024 + qd * 8;
        f32x4 oacc = {};
        for (int kt = 0; kt < 32; kt++) {
            f32x4 x = *(const f32x4*)&sc[swz(ln, kt * 32 + qd * 8)];
            f32x4 y = *(const f32x4*)&sc[swz(ln, kt * 32 + qd * 8 + 4)];
            short8 a = pack8(x, y);
            short8 bf = *(const short8*)(vrow + kt * 32);
            oacc = MFMA16(a, bf, oacc);
        }
#pragma unroll
        for (int r = 0; r < 4; r++) {
            int sl = qd * 4 + r;
            int d = w * 16 + ln;
            ctx[((long)(b * 1024 + s0 + sl)) * 512 + h * 64 + d] = f2bf(oacc[r]);
        }
    }

    // ---- attn dump last: stores drain at kernel end (free) ----
#pragma unroll
    for (int i = 0; i < 16; i++) {
        f32x4 v = *(const f32x4*)&sc[swz(i, tid * 4)];
        __builtin_nontemporal_store(v, (f32x4*)&attn_base[i * 1024 + tid * 4]);
    }
}

extern "C" void kernel_launch(void* const* d_in, const int* in_sizes, int n_in,
                              void* d_out, int out_size, void* d_ws, size_t ws_size,
                              hipStream_t stream) {
    (void)in_sizes; (void)n_in; (void)out_size; (void)ws_size;
    const float* query   = (const float*)d_in[0];
    const float* key     = (const float*)d_in[1];
    const float* value   = (const float*)d_in[2];
    const float* pos_emb = (const float*)d_in[3];
    const float* Wq = (const float*)d_in[4];
    const float* bq = (const float*)d_in[5];
    const float* Wk = (const float*)d_in[6];
    const float* bk = (const float*)d_in[7];
    const float* Wv = (const float*)d_in[8];
    const float* bv = (const float*)d_in[9];
    const float* Wo = (const float*)d_in[10];
    const float* bo = (const float*)d_in[11];
    const float* Wp = (const float*)d_in[12];
    const float* bp = (const float*)d_in[13];

    // workspace layout (bf16 u16 elements)
    u16* qin  = (u16*)d_ws;            // 4096*512
    u16* kin  = qin + 4096 * 512;
    u16* vin  = kin + 4096 * 512;
    u16* wqb  = vin + 4096 * 512;      // 512*512 each
    u16* wkb  = wqb + 512 * 512;
    u16* wvb  = wkb + 512 * 512;
    u16* wob  = wvb + 512 * 512;
    u16* relb = wob + 512 * 512;       // 2048*64 (row 2047 read-garbage, discarded)
    u16* qws  = relb + 2048 * 64;      // [B,H,S,64]
    u16* kws  = qws + 4 * 8 * 1024 * 64;
    u16* vtws = kws + 4 * 8 * 1024 * 64; // [B,H,64,S]
    u16* ctx  = qin; // alias: qin dead after q-projection

    float* out  = (float*)d_out;
    float* attn = out + 2097152;
    float* cont = attn + 33554432;
    float* pos  = cont + 33554432;

    PrepArgs ca;
    ca.s[0] = query; ca.d[0] = qin;
    ca.s[1] = key;   ca.d[1] = kin;
    ca.s[2] = value; ca.d[2] = vin;
    ca.s[3] = Wq;    ca.d[3] = wqb;
    ca.s[4] = Wk;    ca.d[4] = wkb;
    ca.s[5] = Wv;    ca.d[5] = wvb;
    ca.s[6] = Wo;    ca.d[6] = wob;
    ca.pos_emb = pos_emb; ca.Wp = Wp; ca.bp = bp; ca.rel = relb;
    prep_all<<<dim3(2048, 8), 256, 0, stream>>>(ca);

    ProjArgs pa;
    pa.A[0] = qin;  pa.B[0] = wqb; pa.bias[0] = bq; pa.out[0] = qws;
    pa.A[1] = kin;  pa.B[1] = wkb; pa.bias[1] = bk; pa.out[1] = kws;
    pa.A[2] = wvb;  pa.B[2] = vin; pa.bias[2] = bv; pa.out[2] = vtws;
    proj_all<<<dim3(64, 8, 3), 256, 0, stream>>>(pa);

    score_kernel<<<2048, 256, 0, stream>>>(qws, kws, vtws, relb, attn, cont, pos, ctx);

    gemm_final<<<dim3(64, 8), 256, 0, stream>>>(ctx, wob, bo, out);
}